// Round 2
// baseline (14571.353 us; speedup 1.0000x reference)
//
#include <hip/hip_runtime.h>

// BiLSTM(2 layers, bidir, H=512, E=1024) + FC(24) + CRF llh on MI355X.
// R4: single-XCD rec_k (as R3) hardened after R3's harness failure:
//  - claim spin is BOUNDED (~3ms via s_memrealtime). Timeout -> CAS flips to
//    FALLBACK mode: roles from a global counter, exchange via agent-scope
//    atomics (exact R2 protocol, known-correct). Any residency/dispatch
//    anomaly now degrades to a passing run instead of a hang.
//  - flag poll uses __hip_atomic_fetch_or(ptr, ZERO, WORKGROUP) with ZERO
//    laundered through empty asm: workgroup-scope RMW = global_atomic_or,
//    no sc bits -> executes in the LOCAL XCD L2 (same place producers'
//    write-through stores land). No new load asm; no InstCombine
//    "idempotent rmw -> plain load" hazard; atomics never sit in L1.
//  - role remap dir=(idx>>2)&1 groups same-dir WGs on a CU -> the 4 WGs/CU
//    read the same 32KB h-block and L1 absorbs ~3/4 of per-step L2 traffic.

typedef __bf16 bf16;
typedef _Float16 f16;
typedef __bf16 bf16x8 __attribute__((ext_vector_type(8)));
typedef __bf16 bf16x4 __attribute__((ext_vector_type(4)));
typedef _Float16 f16x4 __attribute__((ext_vector_type(4)));
typedef float f32x4 __attribute__((ext_vector_type(4)));
typedef unsigned int u32;
typedef unsigned long long u64;

#define TT 512
#define BB 32
#define HH 512
#define CC_ 24
#define MROWS 16384   // T*B
#define KDIM 1024     // E == 2H
#define NGATE 2048    // 4H

__device__ __forceinline__ f32x4 mfma16(bf16x8 a, bf16x8 b, f32x4 c) {
  return __builtin_amdgcn_mfma_f32_16x16x32_bf16(a, b, c, 0, 0, 0);
}
__device__ __forceinline__ float sigmoidf_(float x) { return 1.f / (1.f + __expf(-x)); }
__device__ __forceinline__ float tanhf_(float x) {
  float e = __expf(2.f * x);           // inf-safe: x>>0 -> 1-0=1, x<<0 -> 1-2=-1
  return 1.f - 2.f / (e + 1.f);
}

// ---------------- weight conversion fp32 -> bf16 ----------------
__global__ __launch_bounds__(256) void convert_w_k(
    const float* __restrict__ wih, const float* __restrict__ whh, const float* __restrict__ fcw,
    bf16* __restrict__ wihb, bf16* __restrict__ whhb, bf16* __restrict__ fcwb) {
  const int n1 = (2 * 2 * NGATE * KDIM) / 4;
  const int n2 = (2 * 2 * NGATE * HH) / 4;
  const int n3 = (32 * KDIM) / 4;
  int stride = gridDim.x * blockDim.x;
  for (int i = blockIdx.x * blockDim.x + threadIdx.x; i < n1 + n2 + n3; i += stride) {
    float4 v;
    bf16* dst;
    if (i < n1) {
      v = ((const float4*)wih)[i];
      dst = wihb + (size_t)i * 4;
    } else if (i < n1 + n2) {
      int j = i - n1;
      v = ((const float4*)whh)[j];
      dst = whhb + (size_t)j * 4;
    } else {
      int j = i - n1 - n2;
      if ((j >> 8) < CC_) v = ((const float4*)fcw)[j];
      else                v = make_float4(0.f, 0.f, 0.f, 0.f);
      dst = fcwb + (size_t)j * 4;
    }
    bf16x4 o; o[0] = (bf16)v.x; o[1] = (bf16)v.y; o[2] = (bf16)v.z; o[3] = (bf16)v.w;
    *(bf16x4*)dst = o;
  }
}

// ---------------- embedding gather -> xt[t*32+b][1024] bf16 ----------------
__global__ __launch_bounds__(64) void embed_k(const int* __restrict__ x,
                                              const float* __restrict__ emb,
                                              bf16* __restrict__ xt) {
  int row = blockIdx.x;
  int t = row >> 5, b = row & 31;
  int tok = x[b * TT + t];
  const float4* src = (const float4*)(emb + (size_t)tok * KDIM);
  bf16* dst = xt + (size_t)row * KDIM;
  int i = threadIdx.x;
#pragma unroll
  for (int c = 0; c < 4; ++c) {
    float4 v = src[i + 64 * c];
    bf16x4 o; o[0] = (bf16)v.x; o[1] = (bf16)v.y; o[2] = (bf16)v.z; o[3] = (bf16)v.w;
    *(bf16x4*)(dst + (size_t)(i + 64 * c) * 4) = o;
  }
}

// ---------------- input GEMM -> Gin fp16, per-WG layout ----------------
// Gh[dir][wg(64)][row(16384)][jj(8)*4+gate(4)]  (each WG's data contiguous)
__global__ __launch_bounds__(256, 2) void gemm_in_k(
    const bf16* __restrict__ A, const bf16* __restrict__ W,
    const float* __restrict__ bih, const float* __restrict__ bhh,
    f16* __restrict__ Gh) {
  __shared__ bf16 As[128 * 72];
  __shared__ bf16 Ws[128 * 72];
  int dir = blockIdx.z;
  const bf16* Wd = W + (size_t)dir * NGATE * KDIM;
  const float* bi = bih + dir * NGATE;
  const float* bh = bhh + dir * NGATE;
  f16* G = Gh + (size_t)dir * 64 * MROWS * 32;
  int m0 = blockIdx.y * 128;
  int n0 = blockIdx.x * 128;
  int tid = threadIdx.x;
  int lane = tid & 63, wave = tid >> 6;
  int wm = wave >> 1, wn = wave & 1;
  int cn = lane & 15, quad = lane >> 4;

  f32x4 zz = {0.f, 0.f, 0.f, 0.f};
  f32x4 acc[4][4];
#pragma unroll
  for (int a = 0; a < 4; ++a)
#pragma unroll
    for (int b = 0; b < 4; ++b) acc[a][b] = zz;

  for (int k0 = 0; k0 < KDIM; k0 += 64) {
    __syncthreads();
#pragma unroll
    for (int j = 0; j < 4; ++j) {
      int cch = tid + 256 * j;
      int row = cch >> 3, kq = cch & 7;
      *(bf16x8*)&As[row * 72 + kq * 8] =
          *(const bf16x8*)&A[(size_t)(m0 + row) * KDIM + k0 + kq * 8];
      *(bf16x8*)&Ws[row * 72 + kq * 8] =
          *(const bf16x8*)&Wd[(size_t)(n0 + row) * KDIM + k0 + kq * 8];
    }
    __syncthreads();
#pragma unroll
    for (int kc = 0; kc < 2; ++kc) {
      bf16x8 af[4], bw[4];
#pragma unroll
      for (int mt = 0; mt < 4; ++mt)
        af[mt] = *(const bf16x8*)&As[(wm * 64 + mt * 16 + cn) * 72 + kc * 32 + quad * 8];
#pragma unroll
      for (int nt = 0; nt < 4; ++nt)
        bw[nt] = *(const bf16x8*)&Ws[(wn * 64 + nt * 16 + cn) * 72 + kc * 32 + quad * 8];
#pragma unroll
      for (int mt = 0; mt < 4; ++mt)
#pragma unroll
        for (int nt = 0; nt < 4; ++nt)
          acc[mt][nt] = mfma16(af[mt], bw[nt], acc[mt][nt]);
    }
  }
#pragma unroll
  for (int nt = 0; nt < 4; ++nt) {
    int n = n0 + wn * 64 + nt * 16 + cn;
    float bias = bi[n] + bh[n];
    int col = n & 511, gate = n >> 9;
    size_t base = (size_t)(col >> 3) * MROWS * 32 + (size_t)(col & 7) * 4 + gate;
#pragma unroll
    for (int mt = 0; mt < 4; ++mt) {
#pragma unroll
      for (int r = 0; r < 4; ++r) {
        int row = m0 + wm * 64 + mt * 16 + quad * 4 + r;
        G[base + (size_t)row * 32] = (f16)(acc[mt][nt][r] + bias);
      }
    }
  }
}

// ---------------- persistent recurrence ----------------
// LOCAL mode: 128 winners co-resident on ONE XCD; plain stores + workgroup-
//   scope atomic_or polls, all serviced by the local XCD L2.
// FALLBACK mode: R2's agent-scope protocol (MALL-coherent, any placement).
// hx[dir][t] is a 32KB block in A-frag order: [kk(16)][piece(4)][lane(64)] x 8B
//   piece = (row>=16)*2 + half;  slot lane = (row&15) + k_quad*16.
template <bool LOCAL>
__device__ __forceinline__ void rec_loop(
    int dir, int wg, int lane,
    const f16* __restrict__ Gin, const bf16* __restrict__ Whh,
    bf16* __restrict__ hbuf, u64* __restrict__ hx, u32* __restrict__ flags,
    bf16* __restrict__ Bl, bf16 (*__restrict__ hS)[8]) {
  int cn = lane & 15, quad = lane >> 4;
  int j0 = wg * 8;
  const bf16* Wd = Whh + (size_t)dir * NGATE * HH;
  const f16* Gw = Gin + ((size_t)dir * 64 + wg) * MROWS * 32;
  u64* hxd = hx + (size_t)dir * TT * 4096;
  u32* fl = flags + (size_t)dir * TT * 64;

  for (int c = lane; c < 2 * 16 * 64; c += 64) {
    int col = c >> 6;
    int kc8 = c & 63;
    int nt = col >> 4, ccn = col & 15;
    int gate = nt * 2 + (ccn >> 3);
    int jj_ = ccn & 7;
    int n = gate * HH + j0 + jj_;
    *(bf16x8*)&Bl[col * 520 + kc8 * 8] = *(const bf16x8*)&Wd[(size_t)n * HH + kc8 * 8];
  }
  __syncthreads();

  float cst[2][4];
#pragma unroll
  for (int mt = 0; mt < 2; ++mt)
#pragma unroll
    for (int r = 0; r < 4; ++r) cst[mt][r] = 0.f;
  bool active = cn < 8;
  int jj = cn & 7;
  f32x4 zz = {0.f, 0.f, 0.f, 0.f};

  // per-lane pack/store geometry (constant across steps)
  int pb = lane >> 1, half = lane & 1;                 // lane packs row pb, cols half*4..+3
  int sIdx = (j0 >> 5) * 256 + (((pb >= 16) ? 2 : 0) + half) * 64 +
             ((j0 >> 3) & 3) * 16 + (pb & 15);         // 8B slot within hx[t]
  size_t hbOff = ((size_t)pb * KDIM + dir * HH + j0 + half * 4);  // within row t*BB

  // opaque zero: keeps fetch_or from being InstCombine'd into a plain load
  u32 zero = 0;
  asm volatile("" : "+v"(zero));

  // prefetch step-0 gate pre-activations
  f16x4 gpn[2][4];
  {
    int t0 = dir ? (TT - 1) : 0;
    if (active) {
#pragma unroll
      for (int mt = 0; mt < 2; ++mt)
#pragma unroll
        for (int r = 0; r < 4; ++r) {
          int b = mt * 16 + quad * 4 + r;
          gpn[mt][r] = *(const f16x4*)&Gw[(size_t)(t0 * BB + b) * 32 + jj * 4];
        }
    }
  }

  for (int s = 0; s < TT; ++s) {
    int t = dir ? (TT - 1 - s) : s;
    f32x4 acc[2][2];
    acc[0][0] = zz; acc[0][1] = zz; acc[1][0] = zz; acc[1][1] = zz;
    if (s > 0) {
      int tp = dir ? (t + 1) : (t - 1);
      u32* f = fl + (size_t)(s - 1) * 64;
      for (;;) {
        u32 v;
        if constexpr (LOCAL)
          v = __hip_atomic_fetch_or(&f[lane], zero, __ATOMIC_RELAXED,
                                    __HIP_MEMORY_SCOPE_WORKGROUP);   // L2-local read
        else
          v = __hip_atomic_load(&f[lane], __ATOMIC_RELAXED, __HIP_MEMORY_SCOPE_AGENT);
        if (__all(v != 0u)) break;
        __builtin_amdgcn_s_sleep(1);
      }
      asm volatile("s_waitcnt vmcnt(0)" ::: "memory");  // acquire fence
      const u64* hb8 = hxd + (size_t)tp * 4096;
#pragma unroll 4
      for (int kk = 0; kk < 16; ++kk) {
        union { u64 u[2]; bf16x8 v; } a0, a1;
        if constexpr (LOCAL) {
          a0.u[0] = hb8[kk * 256 + lane];          // plain: L1-cacheable, lines
          a0.u[1] = hb8[kk * 256 + 64 + lane];     // only ever filled post-flag
          a1.u[0] = hb8[kk * 256 + 128 + lane];
          a1.u[1] = hb8[kk * 256 + 192 + lane];
        } else {
          a0.u[0] = __hip_atomic_load(&hb8[kk * 256 + lane],       __ATOMIC_RELAXED, __HIP_MEMORY_SCOPE_AGENT);
          a0.u[1] = __hip_atomic_load(&hb8[kk * 256 + 64 + lane],  __ATOMIC_RELAXED, __HIP_MEMORY_SCOPE_AGENT);
          a1.u[0] = __hip_atomic_load(&hb8[kk * 256 + 128 + lane], __ATOMIC_RELAXED, __HIP_MEMORY_SCOPE_AGENT);
          a1.u[1] = __hip_atomic_load(&hb8[kk * 256 + 192 + lane], __ATOMIC_RELAXED, __HIP_MEMORY_SCOPE_AGENT);
        }
        bf16x8 b0 = *(const bf16x8*)&Bl[(0 * 16 + cn) * 520 + kk * 32 + quad * 8];
        bf16x8 b1 = *(const bf16x8*)&Bl[(1 * 16 + cn) * 520 + kk * 32 + quad * 8];
        acc[0][0] = mfma16(a0.v, b0, acc[0][0]);
        acc[0][1] = mfma16(a0.v, b1, acc[0][1]);
        acc[1][0] = mfma16(a1.v, b0, acc[1][0]);
        acc[1][1] = mfma16(a1.v, b1, acc[1][1]);
      }
    }
#pragma unroll
    for (int mt = 0; mt < 2; ++mt) {
#pragma unroll
      for (int r = 0; r < 4; ++r) {
        float ip = acc[mt][0][r], gp = acc[mt][1][r];
        float fp = __shfl(ip, lane + 8);   // f-gate partial lives 8 lanes over
        float op = __shfl(gp, lane + 8);   // o-gate partial lives 8 lanes over
        if (active) {
          float xi = ip + (float)gpn[mt][r][0];
          float xf = fp + (float)gpn[mt][r][1];
          float xg = gp + (float)gpn[mt][r][2];
          float xo = op + (float)gpn[mt][r][3];
          float it = sigmoidf_(xi);
          float ft = sigmoidf_(xf);
          float gt = tanhf_(xg);
          float ot = sigmoidf_(xo);
          float cc = ft * cst[mt][r] + it * gt;
          cst[mt][r] = cc;
          int b = mt * 16 + quad * 4 + r;
          hS[b][jj] = (bf16)(ot * tanhf_(cc));
        }
      }
    }
    __syncthreads();   // 1-wave barrier: order LDS transpose write->read
    u64 pv = *(const u64*)&hS[pb][half * 4];
    if constexpr (LOCAL)
      hxd[(size_t)t * 4096 + sIdx] = pv;                            // write-through -> local L2
    else
      __hip_atomic_store(&hxd[(size_t)t * 4096 + sIdx], pv, __ATOMIC_RELAXED,
                         __HIP_MEMORY_SCOPE_AGENT);
    *(u64*)&hbuf[(size_t)(t * BB) * KDIM + hbOff] = pv;             // cached, next kernel
    asm volatile("s_waitcnt vmcnt(0)" ::: "memory");  // release: h visible before flag
    if (lane == 0) {
      if constexpr (LOCAL)
        fl[(size_t)s * 64 + wg] = 1u;
      else
        __hip_atomic_store(&fl[(size_t)s * 64 + wg], 1u, __ATOMIC_RELAXED,
                           __HIP_MEMORY_SCOPE_AGENT);
    }
    // prefetch NEXT step's gates (overlaps next poll + GEMM; never OOB of Gin)
    int tn = dir ? (t - 1) : (t + 1);
    if (active) {
#pragma unroll
      for (int mt = 0; mt < 2; ++mt)
#pragma unroll
        for (int r = 0; r < 4; ++r) {
          int b = mt * 16 + quad * 4 + r;
          gpn[mt][r] = *(const f16x4*)&Gw[(size_t)(tn * BB + b) * 32 + jj * 4];
        }
    }
  }
}

__global__ __launch_bounds__(64) void rec_k(
    const f16* __restrict__ Gin,     // [2][64][16384][32] fp16
    const bf16* __restrict__ Whh,    // [2][2048][512] bf16
    bf16* __restrict__ hbuf,         // [16384][1024] cached out (next layer)
    u64* __restrict__ hx,            // [2][512][4096] 8B slots
    u32* __restrict__ flags,         // [2][512][64], pre-zeroed
    u32* __restrict__ claim) {       // [0..7]=per-XCD cnt, [8]=mode, [9]=fb role
  __shared__ bf16 Bl[2 * 16 * 520];  // Whh slice as B-frags
  __shared__ bf16 hS[32][8];         // transpose staging for h output
  int lane = threadIdx.x;

  // ---- claim a slot on this WG's XCD; first XCD to 128 residents wins ----
  u32 xcc;
  asm volatile("s_getreg_b32 %0, hwreg(HW_REG_XCC_ID)" : "=s"(xcc));
  xcc &= 7u;
  u32 idx = 0;
  if (lane == 0) idx = atomicAdd(&claim[xcc], 1u);
  idx = (u32)__shfl((int)idx, 0);
  if (idx >= 128u) return;
  if (idx == 127u && lane == 0) atomicCAS(&claim[8], 0u, xcc + 1u);

  u32 w;
  u64 t0 = __builtin_amdgcn_s_memrealtime();
  for (;;) {
    w = __hip_atomic_load(&claim[8], __ATOMIC_RELAXED, __HIP_MEMORY_SCOPE_AGENT);
    if (w != 0u) break;
    if (__builtin_amdgcn_s_memrealtime() - t0 > 300000ull) {  // ~3ms @100MHz
      if (lane == 0) atomicCAS(&claim[8], 0u, 0xFFFFu);       // trigger fallback
    }
    __builtin_amdgcn_s_sleep(8);
  }

  int role;
  bool local;
  if (w == 0xFFFFu) {                 // FALLBACK: agent-scope protocol
    u32 r = 0;
    if (lane == 0) r = atomicAdd(&claim[9], 1u);
    r = (u32)__shfl((int)r, 0);
    if (r >= 128u) return;
    role = (int)r; local = false;
  } else {                            // LOCAL: single-XCD protocol
    if (w != xcc + 1u) return;        // not on the winning XCD
    role = (int)idx; local = true;
  }
  // dir-grouped remap: consecutive roles (likely same CU) share a direction,
  // so the 4 WGs on a CU read the same 32KB h-block (L1 reuse).
  int dir = (role >> 2) & 1;
  int wg  = ((role >> 3) << 2) | (role & 3);

  if (local) rec_loop<true >(dir, wg, lane, Gin, Whh, hbuf, hx, flags, Bl, hS);
  else       rec_loop<false>(dir, wg, lane, Gin, Whh, hbuf, hx, flags, Bl, hS);
}

// ---------------- FC: logits[b][t][c] = h1 @ fcw^T + fcb ----------------
__global__ __launch_bounds__(64) void gemm_fc_k(
    const bf16* __restrict__ hbuf,
    const bf16* __restrict__ fcw,
    const float* __restrict__ fcb,
    float* __restrict__ outp) {
  int m0 = blockIdx.x * 16;
  int lane = threadIdx.x;
  int cn = lane & 15, quad = lane >> 4;
  f32x4 acc0 = {0.f, 0.f, 0.f, 0.f}, acc1 = {0.f, 0.f, 0.f, 0.f};
  for (int k0 = 0; k0 < KDIM; k0 += 32) {
    bf16x8 a  = *(const bf16x8*)&hbuf[(size_t)(m0 + cn) * KDIM + k0 + quad * 8];
    bf16x8 b0 = *(const bf16x8*)&fcw[(size_t)cn * KDIM + k0 + quad * 8];
    bf16x8 b1 = *(const bf16x8*)&fcw[(size_t)(cn + 16) * KDIM + k0 + quad * 8];
    acc0 = mfma16(a, b0, acc0);
    acc1 = mfma16(a, b1, acc1);
  }
#pragma unroll
  for (int r = 0; r < 4; ++r) {
    int row = m0 + quad * 4 + r;
    int t = row >> 5, b = row & 31;
    float* o = outp + (size_t)b * (TT * CC_) + (size_t)t * CC_;
    o[cn] = acc0[r] + fcb[cn];
    int c1 = cn + 16;
    if (c1 < CC_) o[c1] = acc1[r] + fcb[c1];
  }
  if (blockIdx.x == 0 && lane == 0) outp[(size_t)BB * TT * CC_] = 0.f;
}

// ---------------- CRF: one WG per batch element ----------------
__global__ __launch_bounds__(64) void crf_k(
    const float* __restrict__ em,
    const int* __restrict__ labels,
    const float* __restrict__ start_, const float* __restrict__ end_,
    const float* __restrict__ trans, float* __restrict__ result) {
  int b = blockIdx.x;
  int j = threadIdx.x;
  bool act = j < CC_;
  int jc = act ? j : 0;
  float tcol[CC_];
#pragma unroll
  for (int i = 0; i < CC_; ++i) tcol[i] = trans[i * CC_ + jc];
  const float* emb_ = em + (size_t)b * (TT * CC_);
  float alpha = act ? (start_[jc] + emb_[jc]) : -1e30f;
  for (int t = 1; t < TT; ++t) {
    float m = -1e30f;
#pragma unroll
    for (int i = 0; i < CC_; ++i) {
      float ai = __shfl(alpha, i);
      m = fmaxf(m, ai + tcol[i]);
    }
    float ssum = 0.f;
#pragma unroll
    for (int i = 0; i < CC_; ++i) {
      float ai = __shfl(alpha, i);
      ssum += __expf(ai + tcol[i] - m);
    }
    float na = m + __logf(ssum) + emb_[(size_t)t * CC_ + jc];
    alpha = act ? na : -1e30f;
  }
  float v = act ? (alpha + end_[jc]) : -1e30f;
  float mm = v;
#pragma unroll
  for (int off = 32; off; off >>= 1) mm = fmaxf(mm, __shfl_xor(mm, off));
  float e = act ? __expf(v - mm) : 0.f;
#pragma unroll
  for (int off = 32; off; off >>= 1) e += __shfl_xor(e, off);
  float logZ = mm + __logf(e);
  float part = 0.f;
  for (int t = j; t < TT; t += 64) {
    int tag = labels[b * TT + t];
    part += emb_[(size_t)t * CC_ + tag];
    if (t < TT - 1) part += trans[tag * CC_ + labels[b * TT + t + 1]];
  }
#pragma unroll
  for (int off = 32; off; off >>= 1) part += __shfl_xor(part, off);
  if (j == 0) {
    float num = part + start_[labels[b * TT]] + end_[labels[b * TT + TT - 1]];
    atomicAdd(result, logZ - num);
  }
}

extern "C" void kernel_launch(void* const* d_in, const int* in_sizes, int n_in,
                              void* d_out, int out_size, void* d_ws, size_t ws_size,
                              hipStream_t stream) {
  const int*   x      = (const int*)d_in[0];
  const int*   labels = (const int*)d_in[1];
  const float* emb    = (const float*)d_in[2];
  const float* w_ih   = (const float*)d_in[3];
  const float* w_hh   = (const float*)d_in[4];
  const float* b_ih   = (const float*)d_in[5];
  const float* b_hh   = (const float*)d_in[6];
  const float* fc_w   = (const float*)d_in[7];
  const float* fc_b   = (const float*)d_in[8];
  const float* crf_s  = (const float*)d_in[9];
  const float* crf_e  = (const float*)d_in[10];
  const float* crf_t  = (const float*)d_in[11];
  float* out = (float*)d_out;
  (void)in_sizes; (void)n_in; (void)out_size; (void)ws_size;

  // workspace carve-up (~294 MB)
  char* ws = (char*)d_ws;
  bf16* xt    = (bf16*)ws;                         //  33,554,432 B
  bf16* h0    = (bf16*)(ws + 33554432);            //  33,554,432
  bf16* h1    = (bf16*)(ws + 67108864);            //  33,554,432
  bf16* wihb  = (bf16*)(ws + 100663296);           //  16,777,216
  bf16* whhb  = (bf16*)(ws + 117440512);           //   8,388,608
  bf16* fcwb  = (bf16*)(ws + 125829120);           //      65,536
  f16*  gin   = (f16*)(ws + 125894656);            // 134,217,728 (fp16)
  u64*  hx    = (u64*)(ws + 260112384);            //  33,554,432
  u32*  flags = (u32*)(ws + 293666816);            //     524,288
  // claim state lives in the xt region (xt is dead after gemm_in layer 0):
  // zeroed after gemm_in L0, before rec_k L0.
  u32*  claim = (u32*)xt;

  hipMemsetAsync(flags, 0, 2 * 2 * TT * 64 * sizeof(u32), stream);
  convert_w_k<<<2048, 256, 0, stream>>>(w_ih, w_hh, fc_w, wihb, whhb, fcwb);
  embed_k<<<MROWS, 64, 0, stream>>>(x, emb, xt);

  // layer 0
  gemm_in_k<<<dim3(16, 128, 2), 256, 0, stream>>>(xt, wihb, b_ih, b_hh, gin);
  hipMemsetAsync(claim, 0, 128, stream);           // xt fully consumed above
  rec_k<<<2048, 64, 0, stream>>>(gin, whhb, h0, hx, flags, claim);
  // layer 1
  gemm_in_k<<<dim3(16, 128, 2), 256, 0, stream>>>(
      h0, wihb + (size_t)2 * NGATE * KDIM, b_ih + 2 * NGATE, b_hh + 2 * NGATE, gin);
  rec_k<<<2048, 64, 0, stream>>>(
      gin, whhb + (size_t)2 * NGATE * HH, h1, hx, flags + 2 * TT * 64, claim + 16);

  gemm_fc_k<<<MROWS / 16, 64, 0, stream>>>(h1, fcwb, fc_b, out);
  crf_k<<<BB, 64, 0, stream>>>(out, labels, crf_s, crf_e, crf_t,
                               out + (size_t)BB * TT * CC_);
}